// Round 2
// baseline (1064.833 us; speedup 1.0000x reference)
//
#include <hip/hip_runtime.h>
#include <stdint.h>

#define TM 128
#define TN 128
#define BK 64

typedef __attribute__((ext_vector_type(4))) int i32x4;

__device__ __forceinline__ void async16(const void* g, void* l) {
    __builtin_amdgcn_global_load_lds(
        (const __attribute__((address_space(1))) unsigned int*)g,
        (__attribute__((address_space(3))) unsigned int*)l,
        16 /*bytes*/, 0 /*offset*/, 0 /*aux*/);
}

// Harness passes integer inputs as int32. Pack to int8 (16 ints -> 16 bytes/thread).
__global__ void pack_i32_to_i8(const int4* __restrict__ src, int4* __restrict__ dst, int n16) {
    int idx = blockIdx.x * blockDim.x + threadIdx.x;
    int stride = gridDim.x * blockDim.x;
    for (int i = idx; i < n16; i += stride) {
        const int4* s = src + (size_t)i * 4;
        int4 a = s[0], b = s[1], c = s[2], d = s[3];
        int4 o;
        o.x = (a.x & 0xFF) | ((a.y & 0xFF) << 8) | ((a.z & 0xFF) << 16) | (a.w << 24);
        o.y = (b.x & 0xFF) | ((b.y & 0xFF) << 8) | ((b.z & 0xFF) << 16) | (b.w << 24);
        o.z = (c.x & 0xFF) | ((c.y & 0xFF) << 8) | ((c.z & 0xFF) << 16) | (c.w << 24);
        o.w = (d.x & 0xFF) | ((d.y & 0xFF) << 8) | ((d.z & 0xFF) << 16) | (d.w << 24);
        dst[i] = o;
    }
}

// 128x128 tile, 4 waves, each wave 64x64 via 4x4 of mfma_i32_16x16x64_i8.
// A/B frag: lane holds [dim = lane&15][k-block = lane>>4], 16 contiguous bytes
//           (any per-lane k-permutation cancels since A and B use identical LDS indexing)
// C/D     : col = lane&15, row = (lane>>4)*4 + reg  (HW-verified, dtype-independent)
__global__ __launch_bounds__(256, 2) void w8a8_silu_kernel(
    const int8_t* __restrict__ x, const int8_t* __restrict__ w,
    const float* __restrict__ bias, const float* __restrict__ alpha_p,
    float* __restrict__ out, int M, int N, int K)
{
    __shared__ int8_t lds_a[TM * BK];   // 8 KB, row-major [128][64]
    __shared__ int8_t lds_b[TN * BK];   // 8 KB

    const int tid  = threadIdx.x;
    const int lane = tid & 63;
    const int wave = tid >> 6;

    // ---- staging addresses: 256 threads x 16 B x 2 chunks per tile ----
    const int srow  = tid >> 2;           // 0..63
    const int skoff = (tid & 3) * 16;     // 0,16,32,48

    const size_t bm = blockIdx.y, bn = blockIdx.x;
    const int8_t* ga0 = x + (bm * TM + srow) * (size_t)K + skoff;
    const int8_t* ga1 = ga0 + (size_t)64 * K;
    const int8_t* gb0 = w + (bn * TN + srow) * (size_t)K + skoff;
    const int8_t* gb1 = gb0 + (size_t)64 * K;

    // lane-contiguous LDS destinations (wave-uniform base + lane*16)
    int8_t* la0 = lds_a + tid * 16;
    int8_t* la1 = la0 + 4096;
    int8_t* lb0 = lds_b + tid * 16;
    int8_t* lb1 = lb0 + 4096;

    // ---- per-wave output subtile ----
    const int wrow = (wave >> 1) * 64;    // M dim
    const int wcol = (wave & 1) * 64;     // N dim
    const int l15  = lane & 15;
    const int quad = lane >> 4;

    i32x4 acc[4][4] = {};

    for (int k0 = 0; k0 < K; k0 += BK) {
        __syncthreads();                  // prior iter's ds_reads done
        async16(ga0 + k0, la0);
        async16(ga1 + k0, la1);
        async16(gb0 + k0, lb0);
        async16(gb1 + k0, lb1);
        __syncthreads();                  // drains vmcnt -> LDS valid

        i32x4 af[4], bf[4];
#pragma unroll
        for (int t = 0; t < 4; ++t) {
            af[t] = *(const i32x4*)(lds_a + (wrow + t * 16 + l15) * BK + quad * 16);
            bf[t] = *(const i32x4*)(lds_b + (wcol + t * 16 + l15) * BK + quad * 16);
        }
#pragma unroll
        for (int mt = 0; mt < 4; ++mt)
#pragma unroll
            for (int nt = 0; nt < 4; ++nt)
                acc[mt][nt] = __builtin_amdgcn_mfma_i32_16x16x64_i8(
                    af[mt], bf[nt], acc[mt][nt], 0, 0, 0);
    }

    // ---- epilogue: y = alpha*acc + bias; y*sigmoid(y); fp32 store ----
    const float alpha = *alpha_p;
    const int col_base = (int)bn * TN + wcol;
    const int row_base = (int)bm * TM + wrow;

#pragma unroll
    for (int nt = 0; nt < 4; ++nt) {
        const int col = col_base + nt * 16 + l15;
        const float bv = bias[col];
#pragma unroll
        for (int mt = 0; mt < 4; ++mt) {
            const int row0 = row_base + mt * 16 + quad * 4;
#pragma unroll
            for (int r = 0; r < 4; ++r) {
                float y = alpha * (float)acc[mt][nt][r] + bv;
                float s = y / (1.0f + __expf(-y));
                out[(size_t)(row0 + r) * N + col] = s;
            }
        }
    }
}

extern "C" void kernel_launch(void* const* d_in, const int* in_sizes, int n_in,
                              void* d_out, int out_size, void* d_ws, size_t ws_size,
                              hipStream_t stream) {
    const int*   x32   = (const int*)d_in[0];     // integer inputs arrive as int32
    const int*   w32   = (const int*)d_in[1];
    const float* bias  = (const float*)d_in[2];
    const float* alpha = (const float*)d_in[3];
    float*       out   = (float*)d_out;

    const int N = in_sizes[2];             // 11008
    const int K = in_sizes[1] / N;         // 4096
    const int M = in_sizes[0] / K;         // 8192

    // pack into workspace: [x8 (M*K)] [w8 (N*K)]
    int8_t* x8 = (int8_t*)d_ws;
    int8_t* w8 = x8 + (size_t)M * K;

    {
        int n16 = (M * (long long)K) / 16;
        pack_i32_to_i8<<<2048, 256, 0, stream>>>((const int4*)x32, (int4*)x8, (int)n16);
    }
    {
        int n16 = ((long long)N * K) / 16;
        pack_i32_to_i8<<<2048, 256, 0, stream>>>((const int4*)w32, (int4*)w8, (int)n16);
    }

    dim3 grid(N / TN, M / TM);             // (86, 64)
    w8a8_silu_kernel<<<grid, 256, 0, stream>>>(x8, w8, bias, alpha, out, M, N, K);
}